// Round 1
// baseline (192.259 us; speedup 1.0000x reference)
//
#include <hip/hip_runtime.h>

// Problem constants
#define B_     8
#define T_     32
#define N_     10
#define TN_    320      // T*N
#define DOBJ_  2048
#define NV_    157
#define NC_    353
#define DEMB_  512
#define DVERB_ 2048
#define DOUT_  2560
#define MPAD_  192      // NV padded to 3*64 for GEMM M-tiling

// Workspace layout (byte offsets, all 256-aligned)
#define OFF_CLS   0          // int[B_*TN_]            = 10240 B
#define OFF_CNT   10240      // float[B_*MPAD_]        = 6144 B
#define OFF_SUBA  16384      // float[B_*TN_*MPAD_]    = 1966080 B
#define OFF_FT    1982464    // float[B_*DOBJ_*MPAD_]  = 12582912 B
#define OFF_PART  14565376   // float[4*B_*MPAD_*DEMB_]= 12582912 B
// total: 27148288 bytes

// ---------------------------------------------------------------------------
// cls[b,i] = last nonzero index of obj_id row (353 entries), or 0 if all zero.
// One wave (64 lanes) per row; ballot-based scan.
__global__ void k_cls(const int* __restrict__ obj_id, int* __restrict__ cls)
{
    int row  = blockIdx.x * 4 + (threadIdx.x >> 6);
    int lane = threadIdx.x & 63;
    if (row >= B_ * TN_) return;
    const int* p = obj_id + (size_t)row * NC_;
    int last = -1;
    #pragma unroll
    for (int base = 0; base < 384; base += 64) {
        int idx = base + lane;
        int v = (idx < NC_) ? p[idx] : 0;
        unsigned long long m = __ballot(v != 0);
        if (m) last = base + 63 - __clzll(m);
    }
    if (lane == 0) cls[row] = (last < 0) ? 0 : last;
}

// ---------------------------------------------------------------------------
// subA[b,i,v] = A_o2v[v, cls[b,i]] / T   (padded to MPAD_ with zeros)
__global__ void k_subA(const float* __restrict__ A, const int* __restrict__ cls,
                       float* __restrict__ subA)
{
    int id = blockIdx.x * 256 + threadIdx.x;   // B_*TN_*MPAD_ total
    if (id >= B_ * TN_ * MPAD_) return;
    int v = id % MPAD_;
    int row = id / MPAD_;
    float val = 0.f;
    if (v < NV_) {
        int c = cls[row];
        val = A[v * NC_ + c] * (1.0f / T_);
    }
    subA[id] = val;
}

// ---------------------------------------------------------------------------
// cnt[b,v] = sum_i subA[b,i,v]   (already has 1/T folded in)
__global__ void k_cnt(const float* __restrict__ subA, float* __restrict__ cnt)
{
    int b = blockIdx.x;
    int v = threadIdx.x;           // blockDim = 192
    const float* p = subA + (size_t)b * TN_ * MPAD_ + v;
    float s = 0.f;
    for (int i = 0; i < TN_; i++) s += p[(size_t)i * MPAD_];
    cnt[b * MPAD_ + v] = s;
}

// ---------------------------------------------------------------------------
// GEMM 1:  Ft[b, n, m] = sum_k subA[b,k,m] * feat[b,k,n]
//   (output stored TRANSPOSED, k-major, so GEMM2 gets the same A layout)
// BM=64, BN=128, BK=16, 256 threads, 8x4 micro-tile.
__global__ __launch_bounds__(256) void k_gemm_c(
    const float* __restrict__ subA, const float* __restrict__ feat,
    float* __restrict__ Ft)
{
    int bx = blockIdx.x;
    int nt = bx & 15;               // 2048/128 = 16 n-tiles
    int mt = (bx >> 4) % 3;         // 192/64   = 3 m-tiles
    int b  = (bx >> 4) / 3;
    const float* Ap = subA + (size_t)b * TN_ * MPAD_;
    const float* Bp = feat + (size_t)b * TN_ * DOBJ_;
    float*       Cp = Ft   + (size_t)b * DOBJ_ * MPAD_;
    int m0 = mt * 64, n0 = nt * 128;

    __shared__ __align__(16) float la[16][64];
    __shared__ __align__(16) float lb[16][128];
    int tid = threadIdx.x, tx = tid & 31, ty = tid >> 5;

    float acc[8][4];
    #pragma unroll
    for (int r = 0; r < 8; r++)
        #pragma unroll
        for (int c = 0; c < 4; c++) acc[r][c] = 0.f;

    for (int kk = 0; kk < TN_; kk += 16) {
        __syncthreads();
        {   // A tile: 16x64 floats = 256 float4, 1/thread
            int ii = tid >> 4, c4 = (tid & 15) << 2;
            *(float4*)&la[ii][c4] =
                *(const float4*)&Ap[(size_t)(kk + ii) * MPAD_ + m0 + c4];
        }
        #pragma unroll
        for (int s = 0; s < 2; s++) {   // B tile: 16x128 = 512 float4, 2/thread
            int f4i = tid + s * 256;
            int ii = f4i >> 5, c4 = (f4i & 31) << 2;
            *(float4*)&lb[ii][c4] =
                *(const float4*)&Bp[(size_t)(kk + ii) * DOBJ_ + n0 + c4];
        }
        __syncthreads();
        #pragma unroll
        for (int ii = 0; ii < 16; ii++) {
            float4 a0 = *(float4*)&la[ii][ty * 8];
            float4 a1 = *(float4*)&la[ii][ty * 8 + 4];
            float4 bq = *(float4*)&lb[ii][tx * 4];
            float a[8] = {a0.x, a0.y, a0.z, a0.w, a1.x, a1.y, a1.z, a1.w};
            float bb[4] = {bq.x, bq.y, bq.z, bq.w};
            #pragma unroll
            for (int r = 0; r < 8; r++)
                #pragma unroll
                for (int c = 0; c < 4; c++)
                    acc[r][c] = fmaf(a[r], bb[c], acc[r][c]);
        }
    }
    // transposed write: Ft[n][m]
    #pragma unroll
    for (int c = 0; c < 4; c++) {
        int n = n0 + tx * 4 + c;
        float4 lo = make_float4(acc[0][c], acc[1][c], acc[2][c], acc[3][c]);
        float4 hi = make_float4(acc[4][c], acc[5][c], acc[6][c], acc[7][c]);
        *(float4*)&Cp[(size_t)n * MPAD_ + m0 + ty * 8]     = lo;
        *(float4*)&Cp[(size_t)n * MPAD_ + m0 + ty * 8 + 4] = hi;
    }
}

// ---------------------------------------------------------------------------
// GEMM 2 (split-K=4):  part[ks,b,m,n] = sum_{k in chunk ks} Ft[b,k,m] * W[k,n]
__global__ __launch_bounds__(256) void k_gemm_d(
    const float* __restrict__ Ft, const float* __restrict__ W,
    float* __restrict__ part)
{
    int bx = blockIdx.x;
    int nt = bx & 3;                // 512/128 = 4 n-tiles
    int rest = bx >> 2;
    int mt = rest % 3;  rest /= 3;  // 3 m-tiles
    int ks = rest & 3;              // 4 K-splits
    int b  = rest >> 2;
    const float* Ap = Ft + (size_t)b * DOBJ_ * MPAD_;
    int m0 = mt * 64, n0 = nt * 128, kb = ks * 512;

    __shared__ __align__(16) float la[16][64];
    __shared__ __align__(16) float lb[16][128];
    int tid = threadIdx.x, tx = tid & 31, ty = tid >> 5;

    float acc[8][4];
    #pragma unroll
    for (int r = 0; r < 8; r++)
        #pragma unroll
        for (int c = 0; c < 4; c++) acc[r][c] = 0.f;

    for (int kk = kb; kk < kb + 512; kk += 16) {
        __syncthreads();
        {
            int ii = tid >> 4, c4 = (tid & 15) << 2;
            *(float4*)&la[ii][c4] =
                *(const float4*)&Ap[(size_t)(kk + ii) * MPAD_ + m0 + c4];
        }
        #pragma unroll
        for (int s = 0; s < 2; s++) {
            int f4i = tid + s * 256;
            int ii = f4i >> 5, c4 = (f4i & 31) << 2;
            *(float4*)&lb[ii][c4] =
                *(const float4*)&W[(size_t)(kk + ii) * DEMB_ + n0 + c4];
        }
        __syncthreads();
        #pragma unroll
        for (int ii = 0; ii < 16; ii++) {
            float4 a0 = *(float4*)&la[ii][ty * 8];
            float4 a1 = *(float4*)&la[ii][ty * 8 + 4];
            float4 bq = *(float4*)&lb[ii][tx * 4];
            float a[8] = {a0.x, a0.y, a0.z, a0.w, a1.x, a1.y, a1.z, a1.w};
            float bb[4] = {bq.x, bq.y, bq.z, bq.w};
            #pragma unroll
            for (int r = 0; r < 8; r++)
                #pragma unroll
                for (int c = 0; c < 4; c++)
                    acc[r][c] = fmaf(a[r], bb[c], acc[r][c]);
        }
    }
    float* P = part + (size_t)(ks * B_ + b) * MPAD_ * DEMB_;
    #pragma unroll
    for (int r = 0; r < 8; r++) {
        int m = m0 + ty * 8 + r;
        *(float4*)&P[(size_t)m * DEMB_ + n0 + tx * 4] =
            make_float4(acc[r][0], acc[r][1], acc[r][2], acc[r][3]);
    }
}

// ---------------------------------------------------------------------------
// out[b,v,e] = sum_ks part[ks,b,v,e] + cnt[b,v]*bias[e]   (e < 512)
__global__ void k_reduce(const float* __restrict__ part, const float* __restrict__ cnt,
                         const float* __restrict__ bias, float* __restrict__ out)
{
    int id = blockIdx.x * 256 + threadIdx.x;
    if (id >= B_ * NV_ * DEMB_) return;
    int e = id & 511;
    int bv = id >> 9;
    int v = bv % NV_;
    int b = bv / NV_;
    float s = cnt[b * MPAD_ + v] * bias[e];
    #pragma unroll
    for (int ks = 0; ks < 4; ks++)
        s += part[((size_t)(ks * B_ + b) * MPAD_ + v) * DEMB_ + e];
    out[(size_t)bv * DOUT_ + e] = s;
}

// ---------------------------------------------------------------------------
// out[b,v,512+d] = mean_t fm[b,t,d]   (same value for every v)
__global__ void k_ctx(const float* __restrict__ fm, float* __restrict__ out)
{
    int id = blockIdx.x * 256 + threadIdx.x;   // B_*DVERB_ total
    int dd = id & 2047;
    int b  = id >> 11;
    const float* p = fm + (size_t)b * T_ * DVERB_ + dd;
    float s = 0.f;
    #pragma unroll
    for (int t = 0; t < T_; t++) s += p[(size_t)t * DVERB_];
    s *= (1.0f / T_);
    float* ob = out + (size_t)b * NV_ * DOUT_ + DEMB_ + dd;
    for (int v = 0; v < NV_; v++) ob[(size_t)v * DOUT_] = s;
}

// ---------------------------------------------------------------------------
extern "C" void kernel_launch(void* const* d_in, const int* in_sizes, int n_in,
                              void* d_out, int out_size, void* d_ws, size_t ws_size,
                              hipStream_t stream)
{
    const float* feat = (const float*)d_in[0];   // (8,32,10,2048)
    const float* fm   = (const float*)d_in[1];   // (8,32,2048)
    const int*   obj  = (const int*)d_in[2];     // (8,32,10,353)
    const float* W    = (const float*)d_in[3];   // (2048,512)
    const float* bias = (const float*)d_in[4];   // (512,)
    const float* A    = (const float*)d_in[5];   // (157,353)
    float* out = (float*)d_out;                  // (8,157,2560)

    char* ws = (char*)d_ws;
    int*   cls  = (int*)(ws + OFF_CLS);
    float* cnt  = (float*)(ws + OFF_CNT);
    float* subA = (float*)(ws + OFF_SUBA);
    float* Ft   = (float*)(ws + OFF_FT);
    float* part = (float*)(ws + OFF_PART);

    k_cls   <<<640, 256, 0, stream>>>(obj, cls);
    k_subA  <<<1920, 256, 0, stream>>>(A, cls, subA);
    k_cnt   <<<8, 192, 0, stream>>>(subA, cnt);
    k_gemm_c<<<384, 256, 0, stream>>>(subA, feat, Ft);
    k_gemm_d<<<384, 256, 0, stream>>>(Ft, W, part);
    k_reduce<<<2512, 256, 0, stream>>>(part, cnt, bias, out);
    k_ctx   <<<64, 256, 0, stream>>>(fm, out);
}

// Round 5
// 151.962 us; speedup vs baseline: 1.2652x; 1.2652x over previous
//
#include <hip/hip_runtime.h>

// Shapes: B=8 T=32 N=10 (I=320) DOBJ=2048 V=157 C=353 DEMB=512 DVERB=2048
// Plan: cls -> subAT(bf16) ; E = feat@W via bf16 MFMA (ET stored [b][512][320] bf16)
//       out[:, :512] = subAT^T-GEMM(ET) + cnt*bias ; out[:, 512:] = broadcast mean_t fm.

typedef __attribute__((ext_vector_type(8))) short short8;     // 8 bf16 = 4 VGPR
typedef __attribute__((ext_vector_type(4))) float f32x4;
typedef __attribute__((ext_vector_type(4))) unsigned short us4;

// Workspace layout (bytes)
#define OFF_CLS 0           // int[2560]
#define OFF_CNT 10240       // float[8*192]
#define OFF_CTX 16384       // float[8*2048]
#define OFF_SAT 81920       // bf16[8*192*320]  subA^T, padded v->192
#define OFF_FB  1064960     // bf16[2560*2048]  feat in bf16
#define OFF_WT  11550720    // bf16[512*2048]   W transposed, bf16
#define OFF_ET  13647872    // bf16[8*512*320]  E transposed per b
// total 16,269,312 B

static __device__ inline unsigned short f2bf(float x) {
    unsigned int u = __builtin_bit_cast(unsigned int, x);
    u += 0x7fffu + ((u >> 16) & 1u);          // round-to-nearest-even
    return (unsigned short)(u >> 16);
}

static __device__ inline void gl16(const void* g, void* l) {
    __builtin_amdgcn_global_load_lds(
        (__attribute__((address_space(1))) void*)(g),
        (__attribute__((address_space(3))) void*)(l), 16, 0, 0);
}

// ---------------------------------------------------------------------------
__global__ void k_cls(const int* __restrict__ obj_id, int* __restrict__ cls)
{
    int row  = blockIdx.x * 4 + (threadIdx.x >> 6);
    int lane = threadIdx.x & 63;
    if (row >= 2560) return;
    const int* p = obj_id + (size_t)row * 353;
    int last = -1;
    #pragma unroll
    for (int base = 0; base < 384; base += 64) {
        int idx = base + lane;
        int v = (idx < 353) ? p[idx] : 0;
        unsigned long long m = __ballot(v != 0);
        if (m) last = base + 63 - __clzll(m);
    }
    if (lane == 0) cls[row] = (last < 0) ? 0 : last;
}

// ---------------------------------------------------------------------------
__global__ void k_cvt_feat(const float* __restrict__ in, unsigned short* __restrict__ out)
{
    size_t id = (size_t)blockIdx.x * 256 + threadIdx.x;   // 1,310,720 threads
    float4 v = *(const float4*)&in[id * 4];
    us4 o = { f2bf(v.x), f2bf(v.y), f2bf(v.z), f2bf(v.w) };
    *(us4*)&out[id * 4] = o;
}

// W[2048][512] f32 -> Wt[512][2048] bf16
__global__ void k_cvt_Wt(const float* __restrict__ W, unsigned short* __restrict__ Wt)
{
    __shared__ float t[32][33];
    int bx = blockIdx.x;                       // 64 r-tiles x 16 c-tiles
    int r0 = (bx >> 4) * 32, c0 = (bx & 15) * 32;
    int tid = threadIdx.x;
    int rr = tid >> 3, cc = (tid & 7) * 4;
    float4 v = *(const float4*)&W[(size_t)(r0 + rr) * 512 + c0 + cc];
    t[rr][cc] = v.x; t[rr][cc+1] = v.y; t[rr][cc+2] = v.z; t[rr][cc+3] = v.w;
    __syncthreads();
    us4 o = { f2bf(t[cc][rr]), f2bf(t[cc+1][rr]), f2bf(t[cc+2][rr]), f2bf(t[cc+3][rr]) };
    *(us4*)&Wt[(size_t)(c0 + rr) * 2048 + r0 + cc] = o;
}

// subAT[b][v(192)][i(320)] = bf16(A[v, cls[b,i]]/32), zero for v>=157
__global__ void k_subAT(const float* __restrict__ A, const int* __restrict__ cls,
                        unsigned short* __restrict__ sAT)
{
    int id = blockIdx.x * 256 + threadIdx.x;   // 491,520
    int i = id % 320;
    int v = (id / 320) % 192;
    int b = id / (320 * 192);
    unsigned short o = 0;
    if (v < 157) o = f2bf(A[v * 353 + cls[b * 320 + i]] * (1.0f / 32.0f));
    sAT[id] = o;
}

// cnt[b][v] = sum_i A[v, cls[b,i]]/32  (exact f32, feeds bias epilogue)
__global__ void k_cnt(const float* __restrict__ A, const int* __restrict__ cls,
                      float* __restrict__ cnt)
{
    __shared__ int lc[320];
    int b = blockIdx.x, v = threadIdx.x;       // 192 threads
    for (int i = v; i < 320; i += 192) lc[i] = cls[b * 320 + i];
    __syncthreads();
    float s = 0.f;
    if (v < 157) {
        for (int i = 0; i < 320; i++) s += A[v * 353 + lc[i]];
        s *= (1.0f / 32.0f);
    }
    cnt[b * 192 + v] = s;
}

// ---------------------------------------------------------------------------
// Shared bf16 MFMA GEMM: C[M][N] = sum_k A[m][k]*B[n][k], A,B K-major bf16.
// Tile 64(M) x 128(N), BK=32, 256 thr = 4 waves, wave = 32x64 (2x4 frags).
// LDS chunk swizzle: slot(r,cl) holds k-chunk cl^((r>>1)&3) (involution) ->
// frag ds_read_b128 spreads over all 32 banks (<=2-way, free per m136).
// MODE 0: A=featb[2560][2048], B=Wt[512][2048], write ET bf16 transposed.
// MODE 1: A=subAT[b][192][320], B=ET[b][512][320], write out f32 + cnt*bias (v<157).
template<int MODE>
__global__ __launch_bounds__(256) void k_gemm(
    const unsigned short* __restrict__ Ap, const unsigned short* __restrict__ Bp,
    void* __restrict__ Cp, const float* __restrict__ cnt, const float* __restrict__ bias)
{
    constexpr int LDA = (MODE == 0) ? 2048 : 320;
    constexpr int LDB = (MODE == 0) ? 2048 : 320;
    constexpr int NK  = (MODE == 0) ? 2048 : 320;

    int bx = blockIdx.x;
    int m0, n0, b = 0, bm = 0;
    size_t aoff = 0, boff = 0;
    if (MODE == 0) { bm = bx >> 2; m0 = bm * 64; n0 = (bx & 3) * 128; }
    else {
        b = bx / 12; int r = bx % 12;
        m0 = (r >> 2) * 64; n0 = (r & 3) * 128;
        aoff = (size_t)b * 192 * 320; boff = (size_t)b * 512 * 320;
    }

    __shared__ __align__(16) unsigned short la[64 * 32];
    __shared__ __align__(16) unsigned short lb[128 * 32];

    int tid = threadIdx.x;
    int lane = tid & 63, w = tid >> 6;
    int wm = (w >> 1) * 32, wn = (w & 1) * 64;

    // staging addresses (pre-swizzled global source, linear LDS dest)
    int ra = tid >> 2;
    int kga = (tid & 3) ^ ((ra >> 1) & 3);
    const unsigned short* ga = Ap + aoff + (size_t)(m0 + ra) * LDA + kga * 8;
    unsigned short* lA = la + tid * 8;

    int rb = tid >> 2;                          // +64 for second chunk
    int kgb = (tid & 3) ^ ((rb >> 1) & 3);      // (r+64)>>1 keeps bits 1:0 -> same kg
    const unsigned short* gb0 = Bp + boff + (size_t)(n0 + rb) * LDB + kgb * 8;
    const unsigned short* gb1 = gb0 + (size_t)64 * LDB;
    unsigned short* lB0 = lb + tid * 8;
    unsigned short* lB1 = lb + (tid + 256) * 8;

    f32x4 acc[2][4] = {};

    for (int kk = 0; kk < NK; kk += 32) {
        __syncthreads();
        gl16(ga + kk, lA);
        gl16(gb0 + kk, lB0);
        gl16(gb1 + kk, lB1);
        __syncthreads();

        short8 af[2], bfr[4];
        #pragma unroll
        for (int mi = 0; mi < 2; mi++) {
            int r = wm + mi * 16 + (lane & 15);
            int kg = (lane >> 4) ^ ((r >> 1) & 3);
            af[mi] = *(const short8*)&la[r * 32 + kg * 8];
        }
        #pragma unroll
        for (int ni = 0; ni < 4; ni++) {
            int r = wn + ni * 16 + (lane & 15);
            int kg = (lane >> 4) ^ ((r >> 1) & 3);
            bfr[ni] = *(const short8*)&lb[r * 32 + kg * 8];
        }
        #pragma unroll
        for (int mi = 0; mi < 2; mi++)
            #pragma unroll
            for (int ni = 0; ni < 4; ni++)
                acc[mi][ni] = __builtin_amdgcn_mfma_f32_16x16x32_bf16(
                    af[mi], bfr[ni], acc[mi][ni], 0, 0, 0);
    }

    if (MODE == 0) {
        // ET[bb][e][il], write 4 consecutive il as bf16x4
        int bb = bm / 5;
        int il0 = (bm % 5) * 64 + wm;
        unsigned short* ET = (unsigned short*)Cp;
        #pragma unroll
        for (int mi = 0; mi < 2; mi++) {
            int il = il0 + mi * 16 + ((lane >> 4) << 2);
            #pragma unroll
            for (int ni = 0; ni < 4; ni++) {
                int e = n0 + wn + ni * 16 + (lane & 15);
                us4 o = { f2bf(acc[mi][ni][0]), f2bf(acc[mi][ni][1]),
                          f2bf(acc[mi][ni][2]), f2bf(acc[mi][ni][3]) };
                *(us4*)&ET[((size_t)bb * 512 + e) * 320 + il] = o;
            }
        }
    } else {
        float* out = (float*)Cp;
        #pragma unroll
        for (int mi = 0; mi < 2; mi++) {
            int v0 = m0 + wm + mi * 16 + ((lane >> 4) << 2);
            #pragma unroll
            for (int ni = 0; ni < 4; ni++) {
                int e = n0 + wn + ni * 16 + (lane & 15);
                float be = bias[e];
                #pragma unroll
                for (int r = 0; r < 4; r++) {
                    int v = v0 + r;
                    if (v < 157)
                        out[((size_t)b * 157 + v) * 2560 + e] =
                            acc[mi][ni][r] + cnt[b * 192 + v] * be;
                }
            }
        }
    }
}

// ---------------------------------------------------------------------------
__global__ void k_ctx_mean(const float* __restrict__ fm, float* __restrict__ ctx)
{
    int id = blockIdx.x * 256 + threadIdx.x;   // 16384
    int b = id >> 11, d = id & 2047;
    const float* p = fm + (size_t)b * 32 * 2048 + d;
    float s = 0.f;
    #pragma unroll
    for (int t = 0; t < 32; t++) s += p[(size_t)t * 2048];
    ctx[id] = s * (1.0f / 32.0f);
}

__global__ void k_ctx_bcast(const float* __restrict__ ctx, float* __restrict__ out)
{
    int id = blockIdx.x * 256 + threadIdx.x;   // 8*157*512 = 643,072
    int q = id & 511;                          // float4 index within 2048
    int bv = id >> 9;
    int b = bv / 157;
    float4 v = *(const float4*)&ctx[((size_t)b << 11) + q * 4];
    *(float4*)&out[(size_t)bv * 2560 + 512 + q * 4] = v;
}

// ---------------------------------------------------------------------------
extern "C" void kernel_launch(void* const* d_in, const int* in_sizes, int n_in,
                              void* d_out, int out_size, void* d_ws, size_t ws_size,
                              hipStream_t stream)
{
    const float* feat = (const float*)d_in[0];
    const float* fm   = (const float*)d_in[1];
    const int*   obj  = (const int*)d_in[2];
    const float* W    = (const float*)d_in[3];
    const float* bias = (const float*)d_in[4];
    const float* A    = (const float*)d_in[5];
    float* out = (float*)d_out;

    char* ws = (char*)d_ws;
    int*            cls   = (int*)(ws + OFF_CLS);
    float*          cnt   = (float*)(ws + OFF_CNT);
    float*          ctx   = (float*)(ws + OFF_CTX);
    unsigned short* sAT   = (unsigned short*)(ws + OFF_SAT);
    unsigned short* featb = (unsigned short*)(ws + OFF_FB);
    unsigned short* Wt    = (unsigned short*)(ws + OFF_WT);
    unsigned short* ET    = (unsigned short*)(ws + OFF_ET);

    k_cls     <<<640, 256, 0, stream>>>(obj, cls);
    k_cvt_feat<<<5120, 256, 0, stream>>>(feat, featb);
    k_cvt_Wt  <<<1024, 256, 0, stream>>>(W, Wt);
    k_subAT   <<<1920, 256, 0, stream>>>(A, cls, sAT);
    k_cnt     <<<8, 192, 0, stream>>>(A, cls, cnt);
    k_gemm<0> <<<160, 256, 0, stream>>>(featb, Wt, ET, nullptr, nullptr);
    k_gemm<1> <<<96, 256, 0, stream>>>(sAT, ET, out, cnt, bias);
    k_ctx_mean<<<64, 256, 0, stream>>>(fm, ctx);
    k_ctx_bcast<<<2512, 256, 0, stream>>>(ctx, out);
}

// Round 8
// 135.610 us; speedup vs baseline: 1.4177x; 1.1206x over previous
//
#include <hip/hip_runtime.h>

// Shapes: B=8 T=32 N=10 (I=320) DOBJ=2048 V=157(pad 192) C=353 DEMB=512 DVERB=2048
// Order-2 dataflow (fewer FLOPs, more blocks, short K-chains):
//   G[b](192x2048)   = subAT[b](192x320) @ featT[b](2048x320)^T   [K=320, 10 iters]
//   out[:, :512]      = G(1536x2048) @ Wt(512x2048)^T + cnt*bias   [K=2048, split-K=4]
//   out[:, 512:]      = broadcast mean_t fm

typedef __attribute__((ext_vector_type(8))) short short8;     // 8 bf16 = 4 VGPR
typedef __attribute__((ext_vector_type(4))) float f32x4;
typedef __attribute__((ext_vector_type(4))) unsigned short us4;

// Workspace layout (bytes)
#define OFF_CLS  0           // int[2560]
#define OFF_CNT  10240       // float[8*192]
#define OFF_CTX  16384       // float[8*2048]
#define OFF_SAT  81920       // bf16[8*192*320]   subA^T
#define OFF_FT   1064960     // bf16[8*2048*320]  feat^T
#define OFF_WT   11550720    // bf16[512*2048]    W^T
#define OFF_G    13647872    // bf16[8*192*2048]  G
#define OFF_PART 19939328    // f32[4*1536*512]   split-K partials
// total 32,522,240 B

static __device__ inline unsigned short f2bf(float x) {
    unsigned int u = __builtin_bit_cast(unsigned int, x);
    u += 0x7fffu + ((u >> 16) & 1u);          // round-to-nearest-even
    return (unsigned short)(u >> 16);
}

static __device__ inline void gl16(const void* g, void* l) {
    __builtin_amdgcn_global_load_lds(
        (__attribute__((address_space(1))) void*)(g),
        (__attribute__((address_space(3))) void*)(l), 16, 0, 0);
}

// ---------------------------------------------------------------------------
__global__ void k_cls(const int* __restrict__ obj_id, int* __restrict__ cls)
{
    int row  = blockIdx.x * 4 + (threadIdx.x >> 6);
    int lane = threadIdx.x & 63;
    if (row >= 2560) return;
    const int* p = obj_id + (size_t)row * 353;
    int last = -1;
    #pragma unroll
    for (int base = 0; base < 384; base += 64) {
        int idx = base + lane;
        int v = (idx < 353) ? p[idx] : 0;
        unsigned long long m = __ballot(v != 0);
        if (m) last = base + 63 - __clzll(m);
    }
    if (lane == 0) cls[row] = (last < 0) ? 0 : last;
}

// ---------------------------------------------------------------------------
// feat[b][i(320)][d(2048)] f32 -> featT[b][d][i] bf16, 32x32 LDS tiles.
__global__ void k_cvt_featT(const float* __restrict__ in, unsigned short* __restrict__ out)
{
    __shared__ float t[32][33];
    int bx = blockIdx.x;                       // 8 * 10(i-tiles) * 64(d-tiles)
    int b  = bx / 640;
    int r  = bx % 640;
    int it = r / 64, dt = r % 64;
    int tid = threadIdx.x;
    int rr = tid >> 3, cc = (tid & 7) * 4;
    float4 v = *(const float4*)&in[((size_t)b * 320 + it * 32 + rr) * 2048 + dt * 32 + cc];
    t[rr][cc] = v.x; t[rr][cc+1] = v.y; t[rr][cc+2] = v.z; t[rr][cc+3] = v.w;
    __syncthreads();
    us4 o = { f2bf(t[cc][rr]), f2bf(t[cc+1][rr]), f2bf(t[cc+2][rr]), f2bf(t[cc+3][rr]) };
    *(us4*)&out[((size_t)b * 2048 + dt * 32 + rr) * 320 + it * 32 + cc] = o;
}

// W[2048][512] f32 -> Wt[512][2048] bf16
__global__ void k_cvt_Wt(const float* __restrict__ W, unsigned short* __restrict__ Wt)
{
    __shared__ float t[32][33];
    int bx = blockIdx.x;                       // 64 r-tiles x 16 c-tiles
    int r0 = (bx >> 4) * 32, c0 = (bx & 15) * 32;
    int tid = threadIdx.x;
    int rr = tid >> 3, cc = (tid & 7) * 4;
    float4 v = *(const float4*)&W[(size_t)(r0 + rr) * 512 + c0 + cc];
    t[rr][cc] = v.x; t[rr][cc+1] = v.y; t[rr][cc+2] = v.z; t[rr][cc+3] = v.w;
    __syncthreads();
    us4 o = { f2bf(t[cc][rr]), f2bf(t[cc+1][rr]), f2bf(t[cc+2][rr]), f2bf(t[cc+3][rr]) };
    *(us4*)&Wt[(size_t)(c0 + rr) * 2048 + r0 + cc] = o;
}

// subAT[b][v(192)][i(320)] = bf16(A[v, cls[b,i]]/32), zero for v>=157
__global__ void k_subAT(const float* __restrict__ A, const int* __restrict__ cls,
                        unsigned short* __restrict__ sAT)
{
    int id = blockIdx.x * 256 + threadIdx.x;   // 491,520
    int i = id % 320;
    int v = (id / 320) % 192;
    int b = id / (320 * 192);
    unsigned short o = 0;
    if (v < 157) o = f2bf(A[v * 353 + cls[b * 320 + i]] * (1.0f / 32.0f));
    sAT[id] = o;
}

// cnt[b][v] = sum_i A[v, cls[b,i]]/32  (exact f32, feeds bias epilogue)
__global__ void k_cnt(const float* __restrict__ A, const int* __restrict__ cls,
                      float* __restrict__ cnt)
{
    __shared__ int lc[320];
    int b = blockIdx.x, v = threadIdx.x;       // 192 threads
    for (int i = v; i < 320; i += 192) lc[i] = cls[b * 320 + i];
    __syncthreads();
    float s = 0.f;
    if (v < 157) {
        for (int i = 0; i < 320; i++) s += A[v * 353 + lc[i]];
        s *= (1.0f / 32.0f);
    }
    cnt[b * 192 + v] = s;
}

// ---------------------------------------------------------------------------
// Double-buffered bf16 MFMA GEMM: C[m][n] = sum_k A[m][k]*B[n][k], K-major bf16.
// Tile 64x128, BK=32, 4 waves (wave = 32x64 = 2x4 frags), LDS 2x(4+8) KB.
// Chunk swizzle cl ^= (r>>1)&3 (involution) -> <=2-way bank aliasing (free, m136).
// MODE 0: A=subAT[b], B=featT[b], NK=320 -> write G bf16 [b][192][2048].
// MODE 1: A=G (M=1536), B=Wt, K-chunk=512 per split ks -> part f32 [ks][1536][512].
template<int MODE>
__global__ __launch_bounds__(256) void k_gemm(
    const unsigned short* __restrict__ Ap, const unsigned short* __restrict__ Bp,
    void* __restrict__ Cp)
{
    constexpr int LDA = (MODE == 0) ? 320 : 2048;
    constexpr int LDB = (MODE == 0) ? 320 : 2048;
    constexpr int NT  = (MODE == 0) ? 10 : 16;   // K-tiles of 32

    int bx = blockIdx.x;
    int m0, n0, kb = 0;
    size_t aoff = 0, boff = 0, coff = 0;
    if (MODE == 0) {
        int b = bx / 48, r = bx % 48;
        m0 = (r >> 4) * 64; n0 = (r & 15) * 128;
        aoff = (size_t)b * 192 * 320; boff = (size_t)b * 2048 * 320;
        coff = (size_t)b * 192 * 2048;
    } else {
        int ks = bx & 3, r = bx >> 2;            // r in 0..95
        m0 = (r >> 2) * 64; n0 = (r & 3) * 128;
        kb = ks * 512; coff = (size_t)ks * 1536 * 512;
    }

    __shared__ __align__(16) unsigned short la[2][64 * 32];
    __shared__ __align__(16) unsigned short lb[2][128 * 32];

    int tid = threadIdx.x, lane = tid & 63, w = tid >> 6;
    int wm = (w >> 1) * 32, wn = (w & 1) * 64;
    int fr = lane & 15, fk = lane >> 4;

    // staging: pre-swizzled global source, linear LDS dest (lane-contig x16B)
    int ra = tid >> 2;
    int kg = (tid & 3) ^ ((ra >> 1) & 3);
    const unsigned short* ga  = Ap + aoff + (size_t)(m0 + ra) * LDA + kg * 8 + kb;
    const unsigned short* gb0 = Bp + boff + (size_t)(n0 + ra) * LDB + kg * 8 + kb;
    const unsigned short* gb1 = gb0 + (size_t)64 * LDB;

    f32x4 acc[2][4] = {};

    auto stage = [&](int buf, int kk) {
        gl16(ga + kk,  &la[buf][tid * 8]);
        gl16(gb0 + kk, &lb[buf][tid * 8]);
        gl16(gb1 + kk, &lb[buf][(tid + 256) * 8]);
    };
    auto compute = [&](int buf) {
        short8 af[2], bf2[4];
        #pragma unroll
        for (int mi = 0; mi < 2; mi++) {
            int r = wm + mi * 16 + fr;
            int kgx = fk ^ ((r >> 1) & 3);
            af[mi] = *(const short8*)&la[buf][r * 32 + kgx * 8];
        }
        #pragma unroll
        for (int ni = 0; ni < 4; ni++) {
            int r = wn + ni * 16 + fr;
            int kgx = fk ^ ((r >> 1) & 3);
            bf2[ni] = *(const short8*)&lb[buf][r * 32 + kgx * 8];
        }
        #pragma unroll
        for (int mi = 0; mi < 2; mi++)
            #pragma unroll
            for (int ni = 0; ni < 4; ni++)
                acc[mi][ni] = __builtin_amdgcn_mfma_f32_16x16x32_bf16(
                    af[mi], bf2[ni], acc[mi][ni], 0, 0, 0);
    };

    stage(0, 0);
    __syncthreads();
    int cur = 0;
    #pragma unroll 1
    for (int t = 1; t < NT; t++) {
        stage(cur ^ 1, t * 32);      // issue next-tile loads (in flight over compute)
        compute(cur);
        __syncthreads();             // drains vmcnt -> buf cur^1 ready
        cur ^= 1;
    }
    compute(cur);

    if (MODE == 0) {
        unsigned short* Gp = (unsigned short*)Cp + coff;
        #pragma unroll
        for (int mi = 0; mi < 2; mi++) {
            int v0 = m0 + wm + mi * 16 + (fk << 2);
            #pragma unroll
            for (int ni = 0; ni < 4; ni++) {
                int d = n0 + wn + ni * 16 + fr;
                #pragma unroll
                for (int r = 0; r < 4; r++)
                    Gp[(size_t)(v0 + r) * 2048 + d] = f2bf(acc[mi][ni][r]);
            }
        }
    } else {
        float* P = (float*)Cp + coff;
        #pragma unroll
        for (int mi = 0; mi < 2; mi++) {
            int mrow = m0 + wm + mi * 16 + (fk << 2);
            #pragma unroll
            for (int ni = 0; ni < 4; ni++) {
                int e = n0 + wn + ni * 16 + fr;
                #pragma unroll
                for (int r = 0; r < 4; r++)
                    P[(size_t)(mrow + r) * 512 + e] = acc[mi][ni][r];
            }
        }
    }
}

// ---------------------------------------------------------------------------
// out[b,v,e] = sum_ks part[ks][b*192+v][e] + cnt[b,v]*bias[e]  (float4 over e)
__global__ void k_reduce(const float* __restrict__ part, const float* __restrict__ cnt,
                         const float* __restrict__ bias, float* __restrict__ out)
{
    int id = blockIdx.x * 256 + threadIdx.x;   // 1536*128
    if (id >= 1536 * 128) return;
    int e4 = id & 127;
    int m  = id >> 7;
    int v = m % 192, b = m / 192;
    if (v >= 157) return;
    float4 s = ((const float4*)bias)[e4];
    float c = cnt[m];
    s.x *= c; s.y *= c; s.z *= c; s.w *= c;
    #pragma unroll
    for (int ks = 0; ks < 4; ks++) {
        float4 p = *(const float4*)&part[((size_t)ks * 1536 + m) * 512 + e4 * 4];
        s.x += p.x; s.y += p.y; s.z += p.z; s.w += p.w;
    }
    *(float4*)&out[((size_t)b * 157 + v) * 2560 + e4 * 4] = s;
}

// ---------------------------------------------------------------------------
__global__ void k_ctx_mean(const float* __restrict__ fm, float* __restrict__ ctx)
{
    int id = blockIdx.x * 256 + threadIdx.x;   // 16384
    int b = id >> 11, d = id & 2047;
    const float* p = fm + (size_t)b * 32 * 2048 + d;
    float s = 0.f;
    #pragma unroll
    for (int t = 0; t < 32; t++) s += p[(size_t)t * 2048];
    ctx[id] = s * (1.0f / 32.0f);
}

__global__ void k_ctx_bcast(const float* __restrict__ ctx, float* __restrict__ out)
{
    int id = blockIdx.x * 256 + threadIdx.x;   // 8*157*512 = 643,072
    if (id >= 8 * 157 * 512) return;
    int q = id & 511;
    int bv = id >> 9;
    int b = bv / 157;
    float4 v = *(const float4*)&ctx[((size_t)b << 11) + q * 4];
    *(float4*)&out[(size_t)bv * 2560 + 512 + q * 4] = v;
}

// ---------------------------------------------------------------------------
extern "C" void kernel_launch(void* const* d_in, const int* in_sizes, int n_in,
                              void* d_out, int out_size, void* d_ws, size_t ws_size,
                              hipStream_t stream)
{
    const float* feat = (const float*)d_in[0];
    const float* fm   = (const float*)d_in[1];
    const int*   obj  = (const int*)d_in[2];
    const float* W    = (const float*)d_in[3];
    const float* bias = (const float*)d_in[4];
    const float* A    = (const float*)d_in[5];
    float* out = (float*)d_out;

    char* ws = (char*)d_ws;
    int*            cls   = (int*)(ws + OFF_CLS);
    float*          cnt   = (float*)(ws + OFF_CNT);
    float*          ctx   = (float*)(ws + OFF_CTX);
    unsigned short* sAT   = (unsigned short*)(ws + OFF_SAT);
    unsigned short* featT = (unsigned short*)(ws + OFF_FT);
    unsigned short* Wt    = (unsigned short*)(ws + OFF_WT);
    unsigned short* G     = (unsigned short*)(ws + OFF_G);
    float*          part  = (float*)(ws + OFF_PART);

    k_cls      <<<640, 256, 0, stream>>>(obj, cls);
    k_cvt_featT<<<5120, 256, 0, stream>>>(feat, featT);
    k_cvt_Wt   <<<1024, 256, 0, stream>>>(W, Wt);
    k_subAT    <<<1920, 256, 0, stream>>>(A, cls, sAT);
    k_cnt      <<<8, 192, 0, stream>>>(A, cls, cnt);
    k_gemm<0>  <<<384, 256, 0, stream>>>(sAT, featT, G);
    k_gemm<1>  <<<384, 256, 0, stream>>>(G, Wt, part);
    k_reduce   <<<768, 256, 0, stream>>>(part, cnt, bias, out);
    k_ctx_mean <<<64, 256, 0, stream>>>(fm, ctx);
    k_ctx_bcast<<<2512, 256, 0, stream>>>(ctx, out);
}

// Round 11
// 128.922 us; speedup vs baseline: 1.4913x; 1.0519x over previous
//
#include <hip/hip_runtime.h>

// B=8 T=32 N=10 (I=320) DOBJ=2048 V=157(pad192) C=353 DEMB=512 DVERB=2048
// 3-kernel pipeline (launch overhead ~10us/kernel dominated previous rounds):
//  K1 k_prep : cvt_Wt || ctx_mean || subAT(inline cls)       [1128 blocks]
//  K2 k_gemmE: E+part = feat(f32,inline cvt) @ Wt, split-K=4 [640 blocks]
//              part[b][e][ks][i] f32
//  K3 k_out  : out[:,:512] = subAT @ (sum_ks part + bias)  + ctx bcast
//              (bias folded: out = sum_i subA*(E+bias) == subA@E + cnt*bias)

typedef __attribute__((ext_vector_type(8))) short short8;      // MFMA a/b frag
typedef __attribute__((ext_vector_type(8))) unsigned short us8;
typedef __attribute__((ext_vector_type(4))) unsigned short us4;
typedef __attribute__((ext_vector_type(4))) float f32x4;

// workspace (bytes)
#define OFF_CTX  0           // f32[8*2048]          = 65536
#define OFF_SAT  65536       // bf16[8*192*320]      = 983040  -> 1048576
#define OFF_WT   1048576     // bf16[512*2048]       = 2097152 -> 3145728
#define OFF_PART 3145728     // f32[8][512][4][320]  = 26214400 -> 29360128

static __device__ inline unsigned short f2bf(float x) {
    unsigned int u = __builtin_bit_cast(unsigned int, x);
    u += 0x7fffu + ((u >> 16) & 1u);
    return (unsigned short)(u >> 16);
}
static __device__ inline void gl16(const void* g, void* l) {
    __builtin_amdgcn_global_load_lds(
        (__attribute__((address_space(1))) void*)(g),
        (__attribute__((address_space(3))) void*)(l), 16, 0, 0);
}

// ---------------------------------------------------------------------------
// K1: [0,1024) W->Wt bf16 ; [1024,1088) ctx mean ; [1088,1128) subAT w/ inline cls
__global__ __launch_bounds__(256) void k_prep(
    const float* __restrict__ W, const float* __restrict__ fm,
    const int* __restrict__ obj, const float* __restrict__ A,
    unsigned short* __restrict__ Wt, float* __restrict__ ctx,
    unsigned short* __restrict__ sAT)
{
    __shared__ float t[32][33];
    __shared__ int lcls[64];
    int bx = blockIdx.x, tid = threadIdx.x;

    if (bx < 1024) {                       // W[2048][512] f32 -> Wt[512][2048] bf16
        int r0 = (bx >> 4) * 32, c0 = (bx & 15) * 32;
        int rr = tid >> 3, cc = (tid & 7) * 4;
        float4 v = *(const float4*)&W[(size_t)(r0 + rr) * 512 + c0 + cc];
        t[rr][cc] = v.x; t[rr][cc+1] = v.y; t[rr][cc+2] = v.z; t[rr][cc+3] = v.w;
        __syncthreads();
        us4 o = { f2bf(t[cc][rr]), f2bf(t[cc+1][rr]), f2bf(t[cc+2][rr]), f2bf(t[cc+3][rr]) };
        *(us4*)&Wt[(size_t)(c0 + rr) * 2048 + r0 + cc] = o;
    } else if (bx < 1088) {                // ctx[b][d] = mean_t fm
        int id = (bx - 1024) * 256 + tid;
        int b = id >> 11, d = id & 2047;
        const float* p = fm + (size_t)b * 32 * 2048 + d;
        float s = 0.f;
        #pragma unroll
        for (int tt = 0; tt < 32; tt++) s += p[(size_t)tt * 2048];
        ctx[id] = s * (1.0f / 32.0f);
    } else {                               // subAT slice, cls computed in-block
        int blk = bx - 1088;               // 0..39
        int b = blk / 5, i0 = (blk % 5) * 64;
        int w = tid >> 6, lane = tid & 63;
        for (int rr = 0; rr < 16; rr++) {
            int il = w * 16 + rr;
            const int* p = obj + ((size_t)b * 320 + i0 + il) * 353;
            int last = -1;
            #pragma unroll
            for (int base = 0; base < 384; base += 64) {
                int idx = base + lane;
                int v = (idx < 353) ? p[idx] : 0;
                unsigned long long m = __ballot(v != 0);
                if (m) last = base + 63 - __clzll(m);
            }
            if (lane == 0) lcls[il] = (last < 0) ? 0 : last;
        }
        __syncthreads();
        #pragma unroll
        for (int q = 0; q < 6; q++) {      // 192v x 8 i8-groups = 1536 units
            int u = q * 256 + tid;
            int v = u >> 3, i8 = u & 7;
            us8 o = {};
            if (v < 157) {
                #pragma unroll
                for (int j = 0; j < 8; j++)
                    o[j] = f2bf(A[v * 353 + lcls[i8 * 8 + j]] * (1.0f / 32.0f));
            }
            *(us8*)&sAT[((size_t)b * 192 + v) * 320 + i0 + i8 * 8] = o;
        }
    }
}

// ---------------------------------------------------------------------------
// K2: part[b][e][ks][i] = sum_{d in ks-chunk} feat[b,i,d]*W[d,e]
// tile 64m x 128n, BK=64, dbuf; A: f32 reg-stage+cvt; B: Wt gl16 (src-preswz).
// In-row 16B-chunk XOR swizzle: chunk ^= (row&7) for 128B rows.
__global__ __launch_bounds__(256) void k_gemmE(
    const float* __restrict__ feat, const unsigned short* __restrict__ Wt,
    float* __restrict__ part)
{
    int bx = blockIdx.x;
    int ks = bx & 3, nt = (bx >> 2) & 3, mt = bx >> 4;     // mt 0..39
    int m0 = mt * 64, n0 = nt * 128, k0 = ks * 512;
    int b = m0 / 320, i0 = m0 % 320;

    __shared__ __align__(16) unsigned short la[2][64 * 64];
    __shared__ __align__(16) unsigned short lb[2][128 * 64];

    int tid = threadIdx.x, lane = tid & 63, w = tid >> 6;
    int wm = (w >> 1) * 32, wn = (w & 1) * 64;
    int fr = lane & 15, fk = lane >> 4;

    // A stage map: row = tid>>2 , 16 f32 at k = (tid&3)*16
    int ar = tid >> 2, acol = (tid & 3) * 16;
    const float* gA = feat + (size_t)(m0 + ar) * 2048 + k0 + acol;
    int asl0 = ((tid & 3) * 2 + 0) ^ (ar & 7);
    int asl1 = ((tid & 3) * 2 + 1) ^ (ar & 7);

    // B stage map (4 gl16 calls): s = c*256+tid -> er = s>>3, ch = s&7
    const unsigned short* gB[4];
    #pragma unroll
    for (int c = 0; c < 4; c++) {
        int s = c * 256 + tid, er = s >> 3, ch = s & 7;
        gB[c] = Wt + (size_t)(n0 + er) * 2048 + k0 + ((ch ^ (er & 7)) << 3);
    }

    f32x4 acc[2][4] = {};
    f32x4 a4[4];

    auto loadA = [&](int kk) {
        #pragma unroll
        for (int j = 0; j < 4; j++) a4[j] = *(const f32x4*)(gA + kk + j * 4);
    };
    auto stageB = [&](int buf, int kk) {
        #pragma unroll
        for (int c = 0; c < 4; c++)
            gl16(gB[c] + kk, &lb[buf][(c * 256 + tid) * 8]);
    };
    auto writeA = [&](int buf) {
        us8 o0, o1;
        #pragma unroll
        for (int j = 0; j < 4; j++) { o0[j] = f2bf(a4[0][j]); o0[j+4] = f2bf(a4[1][j]); }
        #pragma unroll
        for (int j = 0; j < 4; j++) { o1[j] = f2bf(a4[2][j]); o1[j+4] = f2bf(a4[3][j]); }
        *(us8*)&la[buf][ar * 64 + (asl0 << 3)] = o0;
        *(us8*)&la[buf][ar * 64 + (asl1 << 3)] = o1;
    };
    auto compute = [&](int buf) {
        #pragma unroll
        for (int k2 = 0; k2 < 2; k2++) {
            short8 af[2], bf[4];
            #pragma unroll
            for (int mi = 0; mi < 2; mi++) {
                int r = wm + mi * 16 + fr;
                af[mi] = *(const short8*)&la[buf][r * 64 + (((k2 * 4 + fk) ^ (r & 7)) << 3)];
            }
            #pragma unroll
            for (int ni = 0; ni < 4; ni++) {
                int r = wn + ni * 16 + fr;
                bf[ni] = *(const short8*)&lb[buf][r * 64 + (((k2 * 4 + fk) ^ (r & 7)) << 3)];
            }
            #pragma unroll
            for (int mi = 0; mi < 2; mi++)
                #pragma unroll
                for (int ni = 0; ni < 4; ni++)
                    acc[mi][ni] = __builtin_amdgcn_mfma_f32_16x16x32_bf16(
                        af[mi], bf[ni], acc[mi][ni], 0, 0, 0);
        }
    };

    loadA(0); stageB(0, 0); writeA(0);
    __syncthreads();
    int cur = 0;
    #pragma unroll 1
    for (int t = 0; t < 8; t++) {
        if (t < 7) { loadA((t + 1) * 64); stageB(cur ^ 1, (t + 1) * 64); }
        compute(cur);
        if (t < 7) writeA(cur ^ 1);
        __syncthreads();
        cur ^= 1;
    }

    #pragma unroll
    for (int mi = 0; mi < 2; mi++) {
        int i = i0 + wm + mi * 16 + fk * 4;
        #pragma unroll
        for (int ni = 0; ni < 4; ni++) {
            int e = n0 + wn + ni * 16 + fr;
            *(f32x4*)&part[((size_t)(b * 512 + e) * 4 + ks) * 320 + i] = acc[mi][ni];
        }
    }
}

// ---------------------------------------------------------------------------
// K3: blocks [0,96): out[b, v<157, e<512] = subAT@(sum_ks part + bias)
//     blocks [96,2608): ctx broadcast to out[:, :, 512:]
// GEMM: tile 64v x 128e, K=320 (10 iters BK=32), dbuf.
// 64B rows -> 4x16B chunks, swizzle chunk ^= (row&3).
__global__ __launch_bounds__(256) void k_out(
    const unsigned short* __restrict__ sAT, const float* __restrict__ part,
    const float* __restrict__ bias, const float* __restrict__ ctx,
    float* __restrict__ out)
{
    if (blockIdx.x >= 96) {                // ctx broadcast
        int id = (blockIdx.x - 96) * 256 + threadIdx.x;   // 643072
        int q = id & 511, bv = id >> 9, b = bv / 157;
        float4 v = *(const float4*)&ctx[((size_t)b << 11) + q * 4];
        *(float4*)&out[(size_t)bv * 2560 + 512 + q * 4] = v;
        return;
    }
    int bx = blockIdx.x;
    int b = bx / 12, r = bx % 12;
    int v0 = (r >> 2) * 64, e0 = (r & 3) * 128;

    __shared__ __align__(16) unsigned short la[2][64 * 32];
    __shared__ __align__(16) unsigned short lb[2][128 * 32];

    int tid = threadIdx.x, lane = tid & 63, w = tid >> 6;
    int wm = (w >> 1) * 32, wn = (w & 1) * 64;
    int fr = lane & 15, fk = lane >> 4;

    // A gl16: s = tid -> er = tid>>2 (v-row), ch = tid&3
    int aer = tid >> 2, ach = tid & 3;
    const unsigned short* gA = sAT + ((size_t)b * 192 + v0 + aer) * 320
                                   + ((ach ^ (aer & 3)) << 3);
    // B units: u = q*256+tid -> e = u>>3, i4 = u&7
    const float* pb = part + (size_t)b * 512 * 4 * 320;

    f32x4 acc[2][4] = {};
    f32x4 s0, s1, s2, s3;
    float be0, be1, be2, be3;

    auto loadB = [&](int kk) {
        f32x4* sp[4] = { &s0, &s1, &s2, &s3 };
        float* bp[4] = { &be0, &be1, &be2, &be3 };
        #pragma unroll
        for (int q = 0; q < 4; q++) {
            int u = q * 256 + tid, e = u >> 3, i4 = u & 7;
            const float* base = pb + (size_t)(e0 + e) * 4 * 320 + kk + i4 * 4;
            f32x4 s = *(const f32x4*)(base);
            s += *(const f32x4*)(base + 320);
            s += *(const f32x4*)(base + 640);
            s += *(const f32x4*)(base + 960);
            *sp[q] = s;
            *bp[q] = bias[e0 + e];
        }
    };
    auto writeB = [&](int buf) {
        f32x4 sv[4] = { s0, s1, s2, s3 };
        float bv[4] = { be0, be1, be2, be3 };
        #pragma unroll
        for (int q = 0; q < 4; q++) {
            int u = q * 256 + tid, e = u >> 3, i4 = u & 7;
            f32x4 s = sv[q];
            float be = bv[q];
            us4 o = { f2bf(s[0] + be), f2bf(s[1] + be), f2bf(s[2] + be), f2bf(s[3] + be) };
            *(us4*)&lb[buf][e * 32 + ((((i4 >> 1) ^ (e & 3)) << 3) + (i4 & 1) * 4)] = o;
        }
    };
    auto compute = [&](int buf) {
        short8 af[2], bf[4];
        #pragma unroll
        for (int mi = 0; mi < 2; mi++) {
            int rr = wm + mi * 16 + fr;
            af[mi] = *(const short8*)&la[buf][rr * 32 + ((fk ^ (rr & 3)) << 3)];
        }
        #pragma unroll
        for (int ni = 0; ni < 4; ni++) {
            int rr = wn + ni * 16 + fr;
            bf[ni] = *(const short8*)&lb[buf][rr * 32 + ((fk ^ (rr & 3)) << 3)];
        }
        #pragma unroll
        for (int mi = 0; mi < 2; mi++)
            #pragma unroll
            for (int ni = 0; ni < 4; ni++)
                acc[mi][ni] = __builtin_amdgcn_mfma_f32_16x16x32_bf16(
                    af[mi], bf[ni], acc[mi][ni], 0, 0, 0);
    };

    gl16(gA, &la[0][tid * 8]);
    loadB(0); writeB(0);
    __syncthreads();
    int cur = 0;
    #pragma unroll 1
    for (int t = 0; t < 10; t++) {
        if (t < 9) { gl16(gA + (t + 1) * 32, &la[cur ^ 1][tid * 8]); loadB((t + 1) * 32); }
        compute(cur);
        if (t < 9) writeB(cur ^ 1);
        __syncthreads();
        cur ^= 1;
    }

    #pragma unroll
    for (int mi = 0; mi < 2; mi++) {
        int vb = v0 + wm + mi * 16 + fk * 4;
        #pragma unroll
        for (int ni = 0; ni < 4; ni++) {
            int e = e0 + wn + ni * 16 + fr;
            #pragma unroll
            for (int rr = 0; rr < 4; rr++) {
                int v = vb + rr;
                if (v < 157)
                    out[((size_t)b * 157 + v) * 2560 + e] = acc[mi][ni][rr];
            }
        }
    }
}

// ---------------------------------------------------------------------------
extern "C" void kernel_launch(void* const* d_in, const int* in_sizes, int n_in,
                              void* d_out, int out_size, void* d_ws, size_t ws_size,
                              hipStream_t stream)
{
    const float* feat = (const float*)d_in[0];
    const float* fm   = (const float*)d_in[1];
    const int*   obj  = (const int*)d_in[2];
    const float* W    = (const float*)d_in[3];
    const float* bias = (const float*)d_in[4];
    const float* A    = (const float*)d_in[5];
    float* out = (float*)d_out;

    char* ws = (char*)d_ws;
    float*          ctx  = (float*)(ws + OFF_CTX);
    unsigned short* sAT  = (unsigned short*)(ws + OFF_SAT);
    unsigned short* Wt   = (unsigned short*)(ws + OFF_WT);
    float*          part = (float*)(ws + OFF_PART);

    k_prep <<<1128, 256, 0, stream>>>(W, fm, obj, A, Wt, ctx, sAT);
    k_gemmE<<<640, 256, 0, stream>>>(feat, Wt, part);
    k_out  <<<2608, 256, 0, stream>>>(sAT, part, bias, ctx, out);
}

// Round 12
// 118.045 us; speedup vs baseline: 1.6287x; 1.0921x over previous
//
#include <hip/hip_runtime.h>

// B=8 T=32 N=10 (I=320) DOBJ=2048 V=157(pad192) C=353 DEMB=512 DVERB=2048
// 4-kernel pipeline (launch overhead measured ~1us/kernel, work dominates):
//  K0 k_cls  : cls[b,i] = last-nonzero (640 blocks, 1 wave/row)
//  K1 k_prep : feat->bf16 || W->Wt bf16 || ctx mean || subAT gather [2408 blocks]
//  K2 k_gemmE: part[ks] = featb @ Wt  (both operands via gl16, no cvt VALU)
//  K3 k_out  : out[:,:512] = sAT @ (sum_ks part + bias) ; ctx bcast

typedef __attribute__((ext_vector_type(8))) short short8;
typedef __attribute__((ext_vector_type(8))) unsigned short us8;
typedef __attribute__((ext_vector_type(4))) unsigned short us4;
typedef __attribute__((ext_vector_type(4))) float f32x4;

// workspace (bytes)
#define OFF_CTX  0           // f32[8*2048]           = 65536
#define OFF_SAT  65536       // bf16[8*192*320]       -> 1048576
#define OFF_WT   1048576     // bf16[512*2048]        -> 3145728
#define OFF_FB   3145728     // bf16[8*320*2048]      -> 13631488
#define OFF_PART 13631488    // f32[8][512][4][320]   -> 39845888
#define OFF_CLS  39845888    // int[2560]

static __device__ inline unsigned short f2bf(float x) {
    unsigned int u = __builtin_bit_cast(unsigned int, x);
    u += 0x7fffu + ((u >> 16) & 1u);
    return (unsigned short)(u >> 16);
}
static __device__ inline void gl16(const void* g, void* l) {
    __builtin_amdgcn_global_load_lds(
        (__attribute__((address_space(1))) void*)(g),
        (__attribute__((address_space(3))) void*)(l), 16, 0, 0);
}

// ---------------------------------------------------------------------------
__global__ void k_cls(const int* __restrict__ obj_id, int* __restrict__ cls)
{
    int row  = blockIdx.x * 4 + (threadIdx.x >> 6);
    int lane = threadIdx.x & 63;
    if (row >= 2560) return;
    const int* p = obj_id + (size_t)row * 353;
    int last = -1;
    #pragma unroll
    for (int base = 0; base < 384; base += 64) {
        int idx = base + lane;
        int v = (idx < 353) ? p[idx] : 0;
        unsigned long long m = __ballot(v != 0);
        if (m) last = base + 63 - __clzll(m);
    }
    if (lane == 0) cls[row] = (last < 0) ? 0 : last;
}

// ---------------------------------------------------------------------------
// K1 branches: [0,1280) feat->bf16 ; [1280,2304) W->Wt ; [2304,2368) ctx ;
//              [2368,2408) subAT gather from cls
__global__ __launch_bounds__(256) void k_prep(
    const float* __restrict__ W, const float* __restrict__ fm,
    const float* __restrict__ feat, const int* __restrict__ cls,
    const float* __restrict__ A,
    unsigned short* __restrict__ Wt, float* __restrict__ ctx,
    unsigned short* __restrict__ featb, unsigned short* __restrict__ sAT)
{
    __shared__ float t[32][33];
    __shared__ int lcls[64];
    int bx = blockIdx.x, tid = threadIdx.x;

    if (bx < 1280) {                       // feat f32 -> bf16, 16 elem/thread
        size_t id = (size_t)bx * 256 + tid;
        const float* p = feat + id * 16;
        us8 o0, o1;
        #pragma unroll
        for (int j = 0; j < 8; j++) o0[j] = f2bf(p[j]);
        #pragma unroll
        for (int j = 0; j < 8; j++) o1[j] = f2bf(p[8 + j]);
        *(us8*)&featb[id * 16] = o0;
        *(us8*)&featb[id * 16 + 8] = o1;
    } else if (bx < 2304) {                // W[2048][512] -> Wt[512][2048] bf16
        int b2 = bx - 1280;
        int r0 = (b2 >> 4) * 32, c0 = (b2 & 15) * 32;
        int rr = tid >> 3, cc = (tid & 7) * 4;
        float4 v = *(const float4*)&W[(size_t)(r0 + rr) * 512 + c0 + cc];
        t[rr][cc] = v.x; t[rr][cc+1] = v.y; t[rr][cc+2] = v.z; t[rr][cc+3] = v.w;
        __syncthreads();
        us4 o = { f2bf(t[cc][rr]), f2bf(t[cc+1][rr]), f2bf(t[cc+2][rr]), f2bf(t[cc+3][rr]) };
        *(us4*)&Wt[(size_t)(c0 + rr) * 2048 + r0 + cc] = o;
    } else if (bx < 2368) {                // ctx[b][d] = mean_t fm
        int id = (bx - 2304) * 256 + tid;
        int b = id >> 11, d = id & 2047;
        const float* p = fm + (size_t)b * 32 * 2048 + d;
        float s = 0.f;
        #pragma unroll
        for (int tt = 0; tt < 32; tt++) s += p[(size_t)tt * 2048];
        ctx[id] = s * (1.0f / 32.0f);
    } else {                               // subAT gather
        int blk = bx - 2368;               // 0..39
        int b = blk / 5, i0 = (blk % 5) * 64;
        if (tid < 64) lcls[tid] = cls[b * 320 + i0 + tid];
        __syncthreads();
        #pragma unroll
        for (int q = 0; q < 6; q++) {      // 192v x 8 i8-groups
            int u = q * 256 + tid;
            int v = u >> 3, i8 = u & 7;
            us8 o = {};
            if (v < 157) {
                #pragma unroll
                for (int j = 0; j < 8; j++)
                    o[j] = f2bf(A[v * 353 + lcls[i8 * 8 + j]] * (1.0f / 32.0f));
            }
            *(us8*)&sAT[((size_t)b * 192 + v) * 320 + i0 + i8 * 8] = o;
        }
    }
}

// ---------------------------------------------------------------------------
// K2: part[b][e][ks][i] = sum_{d in ks-chunk} featb[b,i,d]*Wt[e,d]
// tile 64m x 128n, BK=64, dbuf; BOTH operands gl16 (src-preswizzle ch^=(row&7)).
__global__ __launch_bounds__(256) void k_gemmE(
    const unsigned short* __restrict__ featb, const unsigned short* __restrict__ Wt,
    float* __restrict__ part)
{
    int bx = blockIdx.x;
    int ks = bx & 3, nt = (bx >> 2) & 3, mt = bx >> 4;     // mt 0..39
    int m0 = mt * 64, n0 = nt * 128, k0 = ks * 512;
    int b = m0 / 320, i0 = m0 % 320;

    __shared__ __align__(16) unsigned short la[2][64 * 64];
    __shared__ __align__(16) unsigned short lb[2][128 * 64];

    int tid = threadIdx.x, lane = tid & 63, w = tid >> 6;
    int wm = (w >> 1) * 32, wn = (w & 1) * 64;
    int fr = lane & 15, fk = lane >> 4;

    const unsigned short* gA[2];
    #pragma unroll
    for (int c = 0; c < 2; c++) {
        int s = c * 256 + tid, ar = s >> 3, ch = s & 7;
        gA[c] = featb + (size_t)(b * 320 + i0 + ar) * 2048 + k0 + ((ch ^ (ar & 7)) << 3);
    }
    const unsigned short* gB[4];
    #pragma unroll
    for (int c = 0; c < 4; c++) {
        int s = c * 256 + tid, er = s >> 3, ch = s & 7;
        gB[c] = Wt + (size_t)(n0 + er) * 2048 + k0 + ((ch ^ (er & 7)) << 3);
    }

    f32x4 acc[2][4] = {};

    auto stage = [&](int buf, int kk) {
        #pragma unroll
        for (int c = 0; c < 2; c++) gl16(gA[c] + kk, &la[buf][(c * 256 + tid) * 8]);
        #pragma unroll
        for (int c = 0; c < 4; c++) gl16(gB[c] + kk, &lb[buf][(c * 256 + tid) * 8]);
    };
    auto compute = [&](int buf) {
        #pragma unroll
        for (int k2 = 0; k2 < 2; k2++) {
            short8 af[2], bf[4];
            #pragma unroll
            for (int mi = 0; mi < 2; mi++) {
                int r = wm + mi * 16 + fr;
                af[mi] = *(const short8*)&la[buf][r * 64 + (((k2 * 4 + fk) ^ (r & 7)) << 3)];
            }
            #pragma unroll
            for (int ni = 0; ni < 4; ni++) {
                int r = wn + ni * 16 + fr;
                bf[ni] = *(const short8*)&lb[buf][r * 64 + (((k2 * 4 + fk) ^ (r & 7)) << 3)];
            }
            #pragma unroll
            for (int mi = 0; mi < 2; mi++)
                #pragma unroll
                for (int ni = 0; ni < 4; ni++)
                    acc[mi][ni] = __builtin_amdgcn_mfma_f32_16x16x32_bf16(
                        af[mi], bf[ni], acc[mi][ni], 0, 0, 0);
        }
    };

    stage(0, 0);
    __syncthreads();
    int cur = 0;
    #pragma unroll 1
    for (int t = 0; t < 8; t++) {
        if (t < 7) stage(cur ^ 1, (t + 1) * 64);
        compute(cur);
        __syncthreads();
        cur ^= 1;
    }

    #pragma unroll
    for (int mi = 0; mi < 2; mi++) {
        int i = i0 + wm + mi * 16 + fk * 4;
        #pragma unroll
        for (int ni = 0; ni < 4; ni++) {
            int e = n0 + wn + ni * 16 + fr;
            *(f32x4*)&part[((size_t)(b * 512 + e) * 4 + ks) * 320 + i] = acc[mi][ni];
        }
    }
}

// ---------------------------------------------------------------------------
// K3: blocks [0,96): out[b, v<157, e<512] = sAT@(sum_ks part + bias)
//     blocks [96,2608): ctx broadcast. (unchanged from verified round-11)
__global__ __launch_bounds__(256) void k_out(
    const unsigned short* __restrict__ sAT, const float* __restrict__ part,
    const float* __restrict__ bias, const float* __restrict__ ctx,
    float* __restrict__ out)
{
    if (blockIdx.x >= 96) {                // ctx broadcast
        int id = (blockIdx.x - 96) * 256 + threadIdx.x;   // 643072
        int q = id & 511, bv = id >> 9, b = bv / 157;
        float4 v = *(const float4*)&ctx[((size_t)b << 11) + q * 4];
        *(float4*)&out[(size_t)bv * 2560 + 512 + q * 4] = v;
        return;
    }
    int bx = blockIdx.x;
    int b = bx / 12, r = bx % 12;
    int v0 = (r >> 2) * 64, e0 = (r & 3) * 128;

    __shared__ __align__(16) unsigned short la[2][64 * 32];
    __shared__ __align__(16) unsigned short lb[2][128 * 32];

    int tid = threadIdx.x, lane = tid & 63, w = tid >> 6;
    int wm = (w >> 1) * 32, wn = (w & 1) * 64;
    int fr = lane & 15, fk = lane >> 4;

    int aer = tid >> 2, ach = tid & 3;
    const unsigned short* gA = sAT + ((size_t)b * 192 + v0 + aer) * 320
                                   + ((ach ^ (aer & 3)) << 3);
    const float* pb = part + (size_t)b * 512 * 4 * 320;

    f32x4 acc[2][4] = {};
    f32x4 s0, s1, s2, s3;
    float be0, be1, be2, be3;

    auto loadB = [&](int kk) {
        f32x4* sp[4] = { &s0, &s1, &s2, &s3 };
        float* bp[4] = { &be0, &be1, &be2, &be3 };
        #pragma unroll
        for (int q = 0; q < 4; q++) {
            int u = q * 256 + tid, e = u >> 3, i4 = u & 7;
            const float* base = pb + (size_t)(e0 + e) * 4 * 320 + kk + i4 * 4;
            f32x4 s = *(const f32x4*)(base);
            s += *(const f32x4*)(base + 320);
            s += *(const f32x4*)(base + 640);
            s += *(const f32x4*)(base + 960);
            *sp[q] = s;
            *bp[q] = bias[e0 + e];
        }
    };
    auto writeB = [&](int buf) {
        f32x4 sv[4] = { s0, s1, s2, s3 };
        float bv[4] = { be0, be1, be2, be3 };
        #pragma unroll
        for (int q = 0; q < 4; q++) {
            int u = q * 256 + tid, e = u >> 3, i4 = u & 7;
            f32x4 s = sv[q];
            float be = bv[q];
            us4 o = { f2bf(s[0] + be), f2bf(s[1] + be), f2bf(s[2] + be), f2bf(s[3] + be) };
            *(us4*)&lb[buf][e * 32 + ((((i4 >> 1) ^ (e & 3)) << 3) + (i4 & 1) * 4)] = o;
        }
    };
    auto compute = [&](int buf) {
        short8 af[2], bf[4];
        #pragma unroll
        for (int mi = 0; mi < 2; mi++) {
            int rr = wm + mi * 16 + fr;
            af[mi] = *(const short8*)&la[buf][rr * 32 + ((fk ^ (rr & 3)) << 3)];
        }
        #pragma unroll
        for (int ni = 0; ni < 4; ni++) {
            int rr = wn + ni * 16 + fr;
            bf[ni] = *(const short8*)&lb[buf][rr * 32 + ((fk ^ (rr & 3)) << 3)];
        }
        #pragma unroll
        for (int mi = 0; mi < 2; mi++)
            #pragma unroll
            for (int ni = 0; ni < 4; ni++)
                acc[mi][ni] = __builtin_amdgcn_mfma_f32_16x16x32_bf16(
                    af[mi], bf[ni], acc[mi][ni], 0, 0, 0);
    };

    gl16(gA, &la[0][tid * 8]);
    loadB(0); writeB(0);
    __syncthreads();
    int cur = 0;
    #pragma unroll 1
    for (int t = 0; t < 10; t++) {
        if (t < 9) { gl16(gA + (t + 1) * 32, &la[cur ^ 1][tid * 8]); loadB((t + 1) * 32); }
        compute(cur);
        if (t < 9) writeB(cur ^ 1);
        __syncthreads();
        cur ^= 1;
    }

    #pragma unroll
    for (int mi = 0; mi < 2; mi++) {
        int vb = v0 + wm + mi * 16 + fk * 4;
        #pragma unroll
        for (int ni = 0; ni < 4; ni++) {
            int e = e0 + wn + ni * 16 + fr;
            #pragma unroll
            for (int rr = 0; rr < 4; rr++) {
                int v = vb + rr;
                if (v < 157)
                    out[((size_t)b * 157 + v) * 2560 + e] = acc[mi][ni][rr];
            }
        }
    }
}

// ---------------------------------------------------------------------------
extern "C" void kernel_launch(void* const* d_in, const int* in_sizes, int n_in,
                              void* d_out, int out_size, void* d_ws, size_t ws_size,
                              hipStream_t stream)
{
    const float* feat = (const float*)d_in[0];
    const float* fm   = (const float*)d_in[1];
    const int*   obj  = (const int*)d_in[2];
    const float* W    = (const float*)d_in[3];
    const float* bias = (const float*)d_in[4];
    const float* A    = (const float*)d_in[5];
    float* out = (float*)d_out;

    char* ws = (char*)d_ws;
    float*          ctx   = (float*)(ws + OFF_CTX);
    unsigned short* sAT   = (unsigned short*)(ws + OFF_SAT);
    unsigned short* Wt    = (unsigned short*)(ws + OFF_WT);
    unsigned short* featb = (unsigned short*)(ws + OFF_FB);
    float*          part  = (float*)(ws + OFF_PART);
    int*            cls   = (int*)(ws + OFF_CLS);

    k_cls  <<<640, 256, 0, stream>>>(obj, cls);
    k_prep <<<2408, 256, 0, stream>>>(W, fm, feat, cls, A, Wt, ctx, featb, sAT);
    k_gemmE<<<640, 256, 0, stream>>>(featb, Wt, part);
    k_out  <<<2608, 256, 0, stream>>>(sAT, part, bias, ctx, out);
}